// Round 2
// baseline (264.461 us; speedup 1.0000x reference)
//
#include <hip/hip_runtime.h>
#include <hip/hip_bf16.h>

#define EPSF 1e-14f
#define RHOF 8.0f

typedef __attribute__((ext_vector_type(8))) short bf16x8;
typedef __attribute__((ext_vector_type(4))) float f32x4;

__device__ __forceinline__ unsigned short f2bf(float f) {
    unsigned int u = __float_as_uint(f);
    u += 0x7fffu + ((u >> 16) & 1u);   // round-to-nearest-even
    return (unsigned short)(u >> 16);
}

// Fused GEMM + exp + row-sum (excluding shifted-diagonal column).
// z=0: sim_image = rim @ tt^T  -> S_im ;  z=1: sim_text = rtt @ im^T -> S_tt
__global__ __launch_bounds__(256) void gemm_expsum(
    const float* __restrict__ rim, const float* __restrict__ rtt,
    const float* __restrict__ im,  const float* __restrict__ tt,
    const float* __restrict__ logit_scale, const int* __restrict__ offset,
    float* __restrict__ S_im, float* __restrict__ S_tt,
    int Bn, int D)
{
    const int z = blockIdx.z;
    const float* Amat = (z == 0) ? rim : rtt;
    const float* Bmat = (z == 0) ? tt  : im;
    float* S = (z == 0) ? S_im : S_tt;

    __shared__ unsigned short As[128 * 40];
    __shared__ unsigned short Bs[128 * 40];

    const int tid = threadIdx.x;
    const int rowBase = blockIdx.y * 128;
    const int colBase = blockIdx.x * 128;

    const int wave = tid >> 6;
    const int lane = tid & 63;
    const int lo   = lane & 15;
    const int qd   = lane >> 4;
    const int m0   = (wave >> 1) * 64;   // wave's row sub-block
    const int n0   = (wave & 1) * 64;    // wave's col sub-block

    f32x4 acc[4][4];
    #pragma unroll
    for (int i = 0; i < 4; ++i)
        #pragma unroll
        for (int j = 0; j < 4; ++j)
            acc[i][j] = (f32x4){0.f, 0.f, 0.f, 0.f};

    for (int k0 = 0; k0 < D; k0 += 32) {
        // stage 128x32 f32 tiles of A and B, converting to bf16 in-register
        #pragma unroll
        for (int it = 0; it < 4; ++it) {
            int qidx = tid + 256 * it;          // 0..1023 float4 slots
            int r = qidx >> 3;                  // row in tile (0..127)
            int c = (qidx & 7) << 2;            // col (0,4,..,28)
            float4 av = *(const float4*)(Amat + (size_t)(rowBase + r) * D + k0 + c);
            float4 bv = *(const float4*)(Bmat + (size_t)(colBase + r) * D + k0 + c);
            int base = r * 40 + c;              // padded row stride 40 (80B, 16B-aligned)
            As[base + 0] = f2bf(av.x); As[base + 1] = f2bf(av.y);
            As[base + 2] = f2bf(av.z); As[base + 3] = f2bf(av.w);
            Bs[base + 0] = f2bf(bv.x); Bs[base + 1] = f2bf(bv.y);
            Bs[base + 2] = f2bf(bv.z); Bs[base + 3] = f2bf(bv.w);
        }
        __syncthreads();

        bf16x8 af[4], bq[4];
        #pragma unroll
        for (int t = 0; t < 4; ++t) {
            af[t] = *(const bf16x8*)&As[(m0 + 16 * t + lo) * 40 + qd * 8];
            bq[t] = *(const bf16x8*)&Bs[(n0 + 16 * t + lo) * 40 + qd * 8];
        }
        #pragma unroll
        for (int ti = 0; ti < 4; ++ti)
            #pragma unroll
            for (int tj = 0; tj < 4; ++tj)
                acc[ti][tj] = __builtin_amdgcn_mfma_f32_16x16x32_bf16(
                    af[ti], bq[tj], acc[ti][tj], 0, 0, 0);
        __syncthreads();
    }

    // Epilogue: exp(ls*sim), mask col == row+offset, row-sum, atomicAdd.
    const float ls = logit_scale[0];
    const int offs = offset[0];
    #pragma unroll
    for (int ti = 0; ti < 4; ++ti) {
        #pragma unroll
        for (int r = 0; r < 4; ++r) {
            int gi = rowBase + m0 + 16 * ti + 4 * qd + r;   // C/D: row = quad*4 + reg
            float rs = 0.f;
            #pragma unroll
            for (int tj = 0; tj < 4; ++tj) {
                int gj = colBase + n0 + 16 * tj + lo;        // C/D: col = lane&15
                float e = expf(ls * acc[ti][tj][r]);
                if (gj == gi + offs) e = 0.f;                // exclude shifted diagonal
                rs += e;
            }
            #pragma unroll
            for (int m = 1; m < 16; m <<= 1) rs += __shfl_xor(rs, m, 64);
            if (lo == 0) atomicAdd(&S[gi], rs);
        }
    }
}

// diag[i] = dot(rim[i], rtt[i]) in fp32 — one wave per row
__global__ __launch_bounds__(256) void diag_kernel(
    const float* __restrict__ rim, const float* __restrict__ rtt,
    float* __restrict__ diag, int D)
{
    int row  = blockIdx.x * 4 + (threadIdx.x >> 6);
    int lane = threadIdx.x & 63;
    const float* a = rim + (size_t)row * D;
    const float* b = rtt + (size_t)row * D;
    float s = 0.f;
    for (int c = lane * 4; c < D; c += 256) {
        float4 av = *(const float4*)(a + c);
        float4 bv = *(const float4*)(b + c);
        s += av.x * bv.x + av.y * bv.y + av.z * bv.z + av.w * bv.w;
    }
    #pragma unroll
    for (int m = 1; m < 64; m <<= 1) s += __shfl_xor(s, m, 64);
    if (lane == 0) diag[row] = s;
}

__global__ __launch_bounds__(256) void final_kernel(
    const float* __restrict__ S_im, const float* __restrict__ S_tt,
    const float* __restrict__ diag,
    const float* __restrict__ ru_im, const float* __restrict__ ru_tt,
    const float* __restrict__ l1_im, const float* __restrict__ l1_tt,
    const float* __restrict__ u_im,  const float* __restrict__ u_tt,
    const float* __restrict__ logit_scale, float* __restrict__ out, int Bn)
{
    const float ls = logit_scale[0];
    const float inv_rw = 1.0f / (float)(Bn - 1);
    float pg = 0.f, lg = 0.f;
    for (int i = threadIdx.x; i < Bn; i += 256) {
        float p1 = l1_im[i] / (u_im[i] + EPSF) + l1_tt[i] / (u_tt[i] + EPSF);
        float dd = expf(-ls * diag[i]);
        float p2 = dd * S_im[i] * inv_rw / (ru_im[i] + EPSF)
                 + dd * S_tt[i] * inv_rw / (ru_tt[i] + EPSF);
        pg += p1 + p2;
        lg += logf(u_im[i]) + logf(u_tt[i]);
    }
    __shared__ float sp[256], sl[256];
    sp[threadIdx.x] = pg; sl[threadIdx.x] = lg;
    __syncthreads();
    for (int s = 128; s > 0; s >>= 1) {
        if (threadIdx.x < s) { sp[threadIdx.x] += sp[threadIdx.x + s];
                               sl[threadIdx.x] += sl[threadIdx.x + s]; }
        __syncthreads();
    }
    if (threadIdx.x == 0) {
        float mean_pg = sp[0] / (float)Bn;          // mean(pg1) + mean(pg2)
        float loss = (mean_pg * 0.5f) / ls
                   + RHOF / ls
                   + (sl[0] / (float)Bn) * 0.5f / ls;
        out[0] = loss;                               // float32 output!
    }
}

extern "C" void kernel_launch(void* const* d_in, const int* in_sizes, int n_in,
                              void* d_out, int out_size, void* d_ws, size_t ws_size,
                              hipStream_t stream) {
    const float* im    = (const float*)d_in[0];
    const float* tt    = (const float*)d_in[1];
    const float* rim   = (const float*)d_in[2];
    const float* rtt   = (const float*)d_in[3];
    const float* ru_im = (const float*)d_in[4];
    const float* ru_tt = (const float*)d_in[5];
    const float* l1_im = (const float*)d_in[6];
    const float* l1_tt = (const float*)d_in[7];
    const float* u_im  = (const float*)d_in[8];
    const float* u_tt  = (const float*)d_in[9];
    const float* lsc   = (const float*)d_in[10];
    const int*   offs  = (const int*)d_in[11];

    const int Bn = in_sizes[4];          // 4096
    const int D  = in_sizes[0] / Bn;     // 1024

    float* S_im = (float*)d_ws;
    float* S_tt = S_im + Bn;
    float* diag = S_tt + Bn;

    hipMemsetAsync(d_ws, 0, (size_t)2 * Bn * sizeof(float), stream);
    diag_kernel<<<Bn / 4, 256, 0, stream>>>(rim, rtt, diag, D);
    dim3 grid(Bn / 128, Bn / 128, 2);
    gemm_expsum<<<grid, 256, 0, stream>>>(rim, rtt, im, tt, lsc, offs, S_im, S_tt, Bn, D);
    final_kernel<<<1, 256, 0, stream>>>(S_im, S_tt, diag, ru_im, ru_tt,
                                        l1_im, l1_tt, u_im, u_tt, lsc,
                                        (float*)d_out, Bn);
}

// Round 3
// 238.975 us; speedup vs baseline: 1.1066x; 1.1066x over previous
//
#include <hip/hip_runtime.h>
#include <hip/hip_bf16.h>

#define EPSF 1e-14f
#define RHOF 8.0f

typedef __attribute__((ext_vector_type(8))) short bf16x8;
typedef __attribute__((ext_vector_type(4))) float f32x4;

#define AS_GLOBAL __attribute__((address_space(1)))
#define AS_LDS    __attribute__((address_space(3)))

__device__ __forceinline__ unsigned short f2bf(float f) {
    unsigned int u = __float_as_uint(f);
    u += 0x7fffu + ((u >> 16) & 1u);   // round-to-nearest-even
    return (unsigned short)(u >> 16);
}

// Convert two f32 matrices to bf16 in tile-packed XOR-swizzled layout.
// Tile = 128 rows x 32 cols bf16 = 512 chunks of 16B. Chunk position
// p = r*4 + (c ^ (r&3)), tiles ordered (rowblock-major, then kblock).
// cpm = chunks per matrix = Bn*D/8.
__global__ __launch_bounds__(256) void convert_pack(
    const float* __restrict__ src0, unsigned short* __restrict__ dst0,
    const float* __restrict__ src1, unsigned short* __restrict__ dst1,
    int D, int cpm)
{
    int gid = blockIdx.x * 256 + threadIdx.x;       // [0, 2*cpm)
    const float* src = (gid >= cpm) ? src1 : src0;
    unsigned short* dst = (gid >= cpm) ? dst1 : dst0;
    int rem = (gid >= cpm) ? gid - cpm : gid;

    int kTiles = D >> 5;                            // 32-wide k tiles
    int T = rem >> 9;                               // tile index
    int p = rem & 511;                              // chunk within tile
    int rb = T / kTiles;
    int kb = T - rb * kTiles;
    int r  = p >> 2;
    int c  = (p & 3) ^ (r & 3);                     // un-swizzle

    const float* s = src + (size_t)(rb * 128 + r) * D + kb * 32 + c * 8;
    float4 a0 = *(const float4*)s;
    float4 a1 = *(const float4*)(s + 4);
    unsigned short o[8] = { f2bf(a0.x), f2bf(a0.y), f2bf(a0.z), f2bf(a0.w),
                            f2bf(a1.x), f2bf(a1.y), f2bf(a1.z), f2bf(a1.w) };
    *(bf16x8*)(dst + (size_t)rem * 8) = *(bf16x8*)o;
}

// m97-style bf16 GEMM + exp + masked row-sum. A,B tile-packed (see above).
// z selects (A0,B0,S0) vs (A1,B1,S1) when gridDim.z==2.
__global__ __launch_bounds__(256) void gemm_expsum(
    const unsigned short* __restrict__ A0, const unsigned short* __restrict__ B0,
    float* __restrict__ S0,
    const unsigned short* __restrict__ A1, const unsigned short* __restrict__ B1,
    float* __restrict__ S1,
    const float* __restrict__ logit_scale, const int* __restrict__ offset,
    int Bn, int D)
{
    const int z = blockIdx.z;
    const unsigned short* A = z ? A1 : A0;
    const unsigned short* B = z ? B1 : B0;
    float* S = z ? S1 : S0;

    __shared__ unsigned short As[4096];   // 128x32 bf16, chunk-packed
    __shared__ unsigned short Bs[4096];

    const int tid  = threadIdx.x;
    const int wave = tid >> 6;
    const int lane = tid & 63;
    const int lo   = lane & 15;
    const int qd   = lane >> 4;
    const int m0   = (wave >> 1) * 64;
    const int n0   = (wave & 1) * 64;
    const int sw   = qd ^ (lo & 3);       // fragment chunk swizzle (const per lane)

    const int kTiles = D >> 5;
    const unsigned short* Atile = A + (size_t)blockIdx.y * kTiles * 4096;
    const unsigned short* Btile = B + (size_t)blockIdx.x * kTiles * 4096;

    f32x4 acc[4][4];
    #pragma unroll
    for (int i = 0; i < 4; ++i)
        #pragma unroll
        for (int j = 0; j < 4; ++j)
            acc[i][j] = (f32x4){0.f, 0.f, 0.f, 0.f};

    for (int kb = 0; kb < kTiles; ++kb) {
        #pragma unroll
        for (int j = 0; j < 2; ++j) {
            int p = j * 256 + tid;                        // global chunk idx
            int ldsoff = (j * 256 + wave * 64) * 8;       // wave-uniform, ushorts
            __builtin_amdgcn_global_load_lds(
                (const AS_GLOBAL unsigned int*)(Atile + p * 8),
                (AS_LDS unsigned int*)&As[ldsoff], 16, 0, 0);
            __builtin_amdgcn_global_load_lds(
                (const AS_GLOBAL unsigned int*)(Btile + p * 8),
                (AS_LDS unsigned int*)&Bs[ldsoff], 16, 0, 0);
        }
        __syncthreads();

        bf16x8 af[4], bq[4];
        #pragma unroll
        for (int t = 0; t < 4; ++t) {
            int ra = m0 + 16 * t + lo;
            af[t] = *(const bf16x8*)&As[(ra * 4 + sw) * 8];
            int rb = n0 + 16 * t + lo;
            bq[t] = *(const bf16x8*)&Bs[(rb * 4 + sw) * 8];
        }
        #pragma unroll
        for (int ti = 0; ti < 4; ++ti)
            #pragma unroll
            for (int tj = 0; tj < 4; ++tj)
                acc[ti][tj] = __builtin_amdgcn_mfma_f32_16x16x32_bf16(
                    af[ti], bq[tj], acc[ti][tj], 0, 0, 0);
        __syncthreads();

        Atile += 4096;
        Btile += 4096;
    }

    // Epilogue: exp(ls*sim), mask col == row+offset, row-sum, atomicAdd.
    const float ls = logit_scale[0];
    const int offs = offset[0];
    const int rowBase = blockIdx.y * 128;
    const int colBase = blockIdx.x * 128;
    #pragma unroll
    for (int ti = 0; ti < 4; ++ti) {
        #pragma unroll
        for (int r = 0; r < 4; ++r) {
            int gi = rowBase + m0 + 16 * ti + 4 * qd + r;   // C/D: row = quad*4+reg
            float rs = 0.f;
            #pragma unroll
            for (int tj = 0; tj < 4; ++tj) {
                int gj = colBase + n0 + 16 * tj + lo;        // C/D: col = lane&15
                float e = __expf(ls * acc[ti][tj][r]);
                if (gj == gi + offs) e = 0.f;                // shifted diagonal
                rs += e;
            }
            #pragma unroll
            for (int m = 1; m < 16; m <<= 1) rs += __shfl_xor(rs, m, 64);
            if (lo == 0) atomicAdd(&S[gi], rs);
        }
    }
}

// diag[i] = dot(rim[i], rtt[i]) in fp32 — one wave per row
__global__ __launch_bounds__(256) void diag_kernel(
    const float* __restrict__ rim, const float* __restrict__ rtt,
    float* __restrict__ diag, int D)
{
    int row  = blockIdx.x * 4 + (threadIdx.x >> 6);
    int lane = threadIdx.x & 63;
    const float* a = rim + (size_t)row * D;
    const float* b = rtt + (size_t)row * D;
    float s = 0.f;
    for (int c = lane * 4; c < D; c += 256) {
        float4 av = *(const float4*)(a + c);
        float4 bv = *(const float4*)(b + c);
        s += av.x * bv.x + av.y * bv.y + av.z * bv.z + av.w * bv.w;
    }
    #pragma unroll
    for (int m = 1; m < 64; m <<= 1) s += __shfl_xor(s, m, 64);
    if (lane == 0) diag[row] = s;
}

__global__ __launch_bounds__(256) void final_kernel(
    const float* __restrict__ S_im, const float* __restrict__ S_tt,
    const float* __restrict__ diag,
    const float* __restrict__ ru_im, const float* __restrict__ ru_tt,
    const float* __restrict__ l1_im, const float* __restrict__ l1_tt,
    const float* __restrict__ u_im,  const float* __restrict__ u_tt,
    const float* __restrict__ logit_scale, float* __restrict__ out, int Bn)
{
    const float ls = logit_scale[0];
    const float inv_rw = 1.0f / (float)(Bn - 1);
    float pg = 0.f, lg = 0.f;
    for (int i = threadIdx.x; i < Bn; i += 256) {
        float p1 = l1_im[i] / (u_im[i] + EPSF) + l1_tt[i] / (u_tt[i] + EPSF);
        float dd = expf(-ls * diag[i]);
        float p2 = dd * S_im[i] * inv_rw / (ru_im[i] + EPSF)
                 + dd * S_tt[i] * inv_rw / (ru_tt[i] + EPSF);
        pg += p1 + p2;
        lg += logf(u_im[i]) + logf(u_tt[i]);
    }
    __shared__ float sp[256], sl[256];
    sp[threadIdx.x] = pg; sl[threadIdx.x] = lg;
    __syncthreads();
    for (int s = 128; s > 0; s >>= 1) {
        if (threadIdx.x < s) { sp[threadIdx.x] += sp[threadIdx.x + s];
                               sl[threadIdx.x] += sl[threadIdx.x + s]; }
        __syncthreads();
    }
    if (threadIdx.x == 0) {
        float mean_pg = sp[0] / (float)Bn;
        float loss = (mean_pg * 0.5f) / ls
                   + RHOF / ls
                   + (sl[0] / (float)Bn) * 0.5f / ls;
        out[0] = loss;
    }
}

extern "C" void kernel_launch(void* const* d_in, const int* in_sizes, int n_in,
                              void* d_out, int out_size, void* d_ws, size_t ws_size,
                              hipStream_t stream) {
    const float* im    = (const float*)d_in[0];
    const float* tt    = (const float*)d_in[1];
    const float* rim   = (const float*)d_in[2];
    const float* rtt   = (const float*)d_in[3];
    const float* ru_im = (const float*)d_in[4];
    const float* ru_tt = (const float*)d_in[5];
    const float* l1_im = (const float*)d_in[6];
    const float* l1_tt = (const float*)d_in[7];
    const float* u_im  = (const float*)d_in[8];
    const float* u_tt  = (const float*)d_in[9];
    const float* lsc   = (const float*)d_in[10];
    const int*   offs  = (const int*)d_in[11];

    const int Bn = in_sizes[4];          // 4096
    const int D  = in_sizes[0] / Bn;     // 1024
    const int cpm = Bn * D / 8;          // 16B chunks per matrix

    char* base = (char*)d_ws;
    float* S_im = (float*)base;
    float* S_tt = S_im + Bn;
    float* diag = S_tt + Bn;
    const size_t headBytes = (size_t)3 * Bn * sizeof(float);
    const size_t matBytes  = (size_t)Bn * D * 2;
    unsigned short* buf0 = (unsigned short*)(base + ((headBytes + 255) & ~(size_t)255));

    hipMemsetAsync(d_ws, 0, (size_t)2 * Bn * sizeof(float), stream);
    diag_kernel<<<Bn / 4, 256, 0, stream>>>(rim, rtt, diag, D);

    const int convGrid = 2 * cpm / 256;
    dim3 ggrid(Bn / 128, Bn / 128, 1);

    if (ws_size >= ((headBytes + 255) & ~(size_t)255) + 4 * matBytes) {
        // 4-buffer one-shot: both GEMMs in a single z=2 dispatch
        unsigned short* bRim = buf0;
        unsigned short* bTt  = buf0 + matBytes / 2;
        unsigned short* bRtt = buf0 + 2 * (matBytes / 2);
        unsigned short* bIm  = buf0 + 3 * (matBytes / 2);
        convert_pack<<<convGrid, 256, 0, stream>>>(rim, bRim, tt, bTt, D, cpm);
        convert_pack<<<convGrid, 256, 0, stream>>>(rtt, bRtt, im, bIm, D, cpm);
        ggrid.z = 2;
        gemm_expsum<<<ggrid, 256, 0, stream>>>(bRim, bTt, S_im, bRtt, bIm, S_tt,
                                               lsc, offs, Bn, D);
    } else {
        // 2-buffer sequential fallback
        unsigned short* bA = buf0;
        unsigned short* bB = buf0 + matBytes / 2;
        convert_pack<<<convGrid, 256, 0, stream>>>(rim, bA, tt, bB, D, cpm);
        gemm_expsum<<<ggrid, 256, 0, stream>>>(bA, bB, S_im, bA, bB, S_im,
                                               lsc, offs, Bn, D);
        convert_pack<<<convGrid, 256, 0, stream>>>(rtt, bA, im, bB, D, cpm);
        gemm_expsum<<<ggrid, 256, 0, stream>>>(bA, bB, S_tt, bA, bB, S_tt,
                                               lsc, offs, Bn, D);
    }

    final_kernel<<<1, 256, 0, stream>>>(S_im, S_tt, diag, ru_im, ru_tt,
                                        l1_im, l1_tt, u_im, u_tt, lsc,
                                        (float*)d_out, Bn);
}

// Round 4
// 230.020 us; speedup vs baseline: 1.1497x; 1.0389x over previous
//
#include <hip/hip_runtime.h>
#include <hip/hip_bf16.h>

#define EPSF 1e-14f
#define RHOF 8.0f

typedef __attribute__((ext_vector_type(8))) short bf16x8;
typedef __attribute__((ext_vector_type(4))) float f32x4;

#define AS_GLOBAL __attribute__((address_space(1)))
#define AS_LDS    __attribute__((address_space(3)))

__device__ __forceinline__ unsigned short f2bf(float f) {
    unsigned int u = __float_as_uint(f);
    u += 0x7fffu + ((u >> 16) & 1u);   // round-to-nearest-even
    return (unsigned short)(u >> 16);
}

// Tile-packed XOR-swizzled bf16 layout. Tile = 128 rows x 32 cols = 512
// 16B chunks. Chunk for (row r, k-chunk j) stored at p = r*4 + (j ^ ((r>>1)&3)).
// Phase-aware swizzle: within each 16-lane quarter-wave of the fragment
// ds_read_b128, banks group = 4*(r&1) + (j ^ ((r>>1)&3)) covers all 8
// four-bank groups exactly twice -> conflict-free (b128 floor).
__device__ __forceinline__ void convert_chunk(
    const float* __restrict__ src, unsigned short* __restrict__ dst,
    int D, int rem)
{
    int kTiles = D >> 5;
    int T = rem >> 9;                   // tile index
    int p = rem & 511;                  // chunk within tile
    int rb = T / kTiles;
    int kb = T - rb * kTiles;
    int r  = p >> 2;
    int j  = (p & 3) ^ ((r >> 1) & 3);  // un-swizzle
    const float* s = src + (size_t)(rb * 128 + r) * D + kb * 32 + j * 8;
    float4 a0 = *(const float4*)s;
    float4 a1 = *(const float4*)(s + 4);
    unsigned short o[8] = { f2bf(a0.x), f2bf(a0.y), f2bf(a0.z), f2bf(a0.w),
                            f2bf(a1.x), f2bf(a1.y), f2bf(a1.z), f2bf(a1.w) };
    *(bf16x8*)(dst + (size_t)rem * 8) = *(bf16x8*)o;
}

// One dispatch: convert all 4 matrices to packed bf16, compute diag, zero S.
__global__ __launch_bounds__(256) void prep4(
    const float* __restrict__ im,  const float* __restrict__ tt,
    const float* __restrict__ rim, const float* __restrict__ rtt,
    unsigned short* __restrict__ bIm,  unsigned short* __restrict__ bTt,
    unsigned short* __restrict__ bRim, unsigned short* __restrict__ bRtt,
    float* __restrict__ S_im, float* __restrict__ S_tt,
    float* __restrict__ diag, int D, int bpm /* blocks per matrix */)
{
    int b = blockIdx.x;
    int nConv = 4 * bpm;
    if (b < nConv) {
        int m = b / bpm;
        int rem = (b - m * bpm) * 256 + threadIdx.x;
        const float* src = (m == 0) ? rim : (m == 1) ? tt : (m == 2) ? rtt : im;
        unsigned short* dst = (m == 0) ? bRim : (m == 1) ? bTt : (m == 2) ? bRtt : bIm;
        convert_chunk(src, dst, D, rem);
    } else {
        int db = b - nConv;                      // 0..Bn/4-1
        int tid = threadIdx.x;
        if (tid < 4) { S_im[db * 4 + tid] = 0.f; S_tt[db * 4 + tid] = 0.f; }
        int row  = db * 4 + (tid >> 6);
        int lane = tid & 63;
        const float* a = rim + (size_t)row * D;
        const float* c = rtt + (size_t)row * D;
        float s = 0.f;
        for (int k = lane * 4; k < D; k += 256) {
            float4 av = *(const float4*)(a + k);
            float4 cv = *(const float4*)(c + k);
            s += av.x * cv.x + av.y * cv.y + av.z * cv.z + av.w * cv.w;
        }
        #pragma unroll
        for (int m2 = 1; m2 < 64; m2 <<= 1) s += __shfl_xor(s, m2, 64);
        if (lane == 0) diag[row] = s;
    }
}

// m97-style bf16 GEMM + exp + masked row-sum. A,B tile-packed (see above).
// z selects (A0,B0,S0) vs (A1,B1,S1) when gridDim.z==2.
__global__ __launch_bounds__(256) void gemm_expsum(
    const unsigned short* __restrict__ A0, const unsigned short* __restrict__ B0,
    float* __restrict__ S0,
    const unsigned short* __restrict__ A1, const unsigned short* __restrict__ B1,
    float* __restrict__ S1,
    const float* __restrict__ logit_scale, const int* __restrict__ offset,
    int Bn, int D)
{
    const int z = blockIdx.z;
    const unsigned short* A = z ? A1 : A0;
    const unsigned short* B = z ? B1 : B0;
    float* S = z ? S1 : S0;

    __shared__ unsigned short As[4096];   // 128x32 bf16, chunk-packed
    __shared__ unsigned short Bs[4096];

    const int tid  = threadIdx.x;
    const int wave = tid >> 6;
    const int lane = tid & 63;
    const int lo   = lane & 15;
    const int qd   = lane >> 4;
    const int m0   = (wave >> 1) * 64;
    const int n0   = (wave & 1) * 64;
    const int sw   = qd ^ ((lo >> 1) & 3);   // phase-aware chunk swizzle

    const int kTiles = D >> 5;
    const unsigned short* Atile = A + (size_t)blockIdx.y * kTiles * 4096;
    const unsigned short* Btile = B + (size_t)blockIdx.x * kTiles * 4096;

    f32x4 acc[4][4];
    #pragma unroll
    for (int i = 0; i < 4; ++i)
        #pragma unroll
        for (int j = 0; j < 4; ++j)
            acc[i][j] = (f32x4){0.f, 0.f, 0.f, 0.f};

    for (int kb = 0; kb < kTiles; ++kb) {
        #pragma unroll
        for (int j = 0; j < 2; ++j) {
            int p = j * 256 + tid;                        // global chunk idx
            int ldsoff = (j * 256 + wave * 64) * 8;       // wave-uniform, ushorts
            __builtin_amdgcn_global_load_lds(
                (const AS_GLOBAL unsigned int*)(Atile + p * 8),
                (AS_LDS unsigned int*)&As[ldsoff], 16, 0, 0);
            __builtin_amdgcn_global_load_lds(
                (const AS_GLOBAL unsigned int*)(Btile + p * 8),
                (AS_LDS unsigned int*)&Bs[ldsoff], 16, 0, 0);
        }
        __syncthreads();

        bf16x8 af[4], bq[4];
        #pragma unroll
        for (int t = 0; t < 4; ++t) {
            int ra = m0 + 16 * t + lo;
            af[t] = *(const bf16x8*)&As[((ra << 2) + sw) * 8];
            int rb = n0 + 16 * t + lo;
            bq[t] = *(const bf16x8*)&Bs[((rb << 2) + sw) * 8];
        }
        #pragma unroll
        for (int ti = 0; ti < 4; ++ti)
            #pragma unroll
            for (int tj = 0; tj < 4; ++tj)
                acc[ti][tj] = __builtin_amdgcn_mfma_f32_16x16x32_bf16(
                    af[ti], bq[tj], acc[ti][tj], 0, 0, 0);
        __syncthreads();

        Atile += 4096;
        Btile += 4096;
    }

    // Epilogue: exp(ls*sim), mask col == row+offset, row-sum, atomicAdd.
    const float ls = logit_scale[0];
    const int offs = offset[0];
    const int rowBase = blockIdx.y * 128;
    const int colBase = blockIdx.x * 128;
    #pragma unroll
    for (int ti = 0; ti < 4; ++ti) {
        #pragma unroll
        for (int r = 0; r < 4; ++r) {
            int gi = rowBase + m0 + 16 * ti + 4 * qd + r;   // C/D: row = quad*4+reg
            float rs = 0.f;
            #pragma unroll
            for (int tj = 0; tj < 4; ++tj) {
                int gj = colBase + n0 + 16 * tj + lo;        // C/D: col = lane&15
                float e = __expf(ls * acc[ti][tj][r]);
                if (gj == gi + offs) e = 0.f;                // shifted diagonal
                rs += e;
            }
            #pragma unroll
            for (int m = 1; m < 16; m <<= 1) rs += __shfl_xor(rs, m, 64);
            if (lo == 0) atomicAdd(&S[gi], rs);
        }
    }
}

// Fallback-path converter (2 matrices, no diag)
__global__ __launch_bounds__(256) void convert2(
    const float* __restrict__ src0, unsigned short* __restrict__ dst0,
    const float* __restrict__ src1, unsigned short* __restrict__ dst1,
    int D, int cpm)
{
    int gid = blockIdx.x * 256 + threadIdx.x;
    const float* src = (gid >= cpm) ? src1 : src0;
    unsigned short* dst = (gid >= cpm) ? dst1 : dst0;
    int rem = (gid >= cpm) ? gid - cpm : gid;
    convert_chunk(src, dst, D, rem);
}

__global__ __launch_bounds__(256) void final_kernel(
    const float* __restrict__ S_im, const float* __restrict__ S_tt,
    const float* __restrict__ diag,
    const float* __restrict__ ru_im, const float* __restrict__ ru_tt,
    const float* __restrict__ l1_im, const float* __restrict__ l1_tt,
    const float* __restrict__ u_im,  const float* __restrict__ u_tt,
    const float* __restrict__ logit_scale, float* __restrict__ out, int Bn)
{
    const float ls = logit_scale[0];
    const float inv_rw = 1.0f / (float)(Bn - 1);
    float pg = 0.f, lg = 0.f;
    for (int i = threadIdx.x; i < Bn; i += 256) {
        float p1 = l1_im[i] / (u_im[i] + EPSF) + l1_tt[i] / (u_tt[i] + EPSF);
        float dd = expf(-ls * diag[i]);
        float p2 = dd * S_im[i] * inv_rw / (ru_im[i] + EPSF)
                 + dd * S_tt[i] * inv_rw / (ru_tt[i] + EPSF);
        pg += p1 + p2;
        lg += logf(u_im[i]) + logf(u_tt[i]);
    }
    __shared__ float sp[256], sl[256];
    sp[threadIdx.x] = pg; sl[threadIdx.x] = lg;
    __syncthreads();
    for (int s = 128; s > 0; s >>= 1) {
        if (threadIdx.x < s) { sp[threadIdx.x] += sp[threadIdx.x + s];
                               sl[threadIdx.x] += sl[threadIdx.x + s]; }
        __syncthreads();
    }
    if (threadIdx.x == 0) {
        float mean_pg = sp[0] / (float)Bn;
        float loss = (mean_pg * 0.5f) / ls
                   + RHOF / ls
                   + (sl[0] / (float)Bn) * 0.5f / ls;
        out[0] = loss;
    }
}

extern "C" void kernel_launch(void* const* d_in, const int* in_sizes, int n_in,
                              void* d_out, int out_size, void* d_ws, size_t ws_size,
                              hipStream_t stream) {
    const float* im    = (const float*)d_in[0];
    const float* tt    = (const float*)d_in[1];
    const float* rim   = (const float*)d_in[2];
    const float* rtt   = (const float*)d_in[3];
    const float* ru_im = (const float*)d_in[4];
    const float* ru_tt = (const float*)d_in[5];
    const float* l1_im = (const float*)d_in[6];
    const float* l1_tt = (const float*)d_in[7];
    const float* u_im  = (const float*)d_in[8];
    const float* u_tt  = (const float*)d_in[9];
    const float* lsc   = (const float*)d_in[10];
    const int*   offs  = (const int*)d_in[11];

    const int Bn = in_sizes[4];          // 4096
    const int D  = in_sizes[0] / Bn;     // 1024
    const int cpm = Bn * D / 8;          // 16B chunks per matrix
    const int bpm = cpm / 256;           // conversion blocks per matrix

    char* base = (char*)d_ws;
    float* S_im = (float*)base;
    float* S_tt = S_im + Bn;
    float* diag = S_tt + Bn;
    const size_t headBytes = ((size_t)3 * Bn * sizeof(float) + 255) & ~(size_t)255;
    const size_t matBytes  = (size_t)Bn * D * 2;
    unsigned short* buf0 = (unsigned short*)(base + headBytes);

    dim3 ggrid(Bn / 128, Bn / 128, 1);

    if (ws_size >= headBytes + 4 * matBytes) {
        // 3 dispatches total: prep4, gemm(z=2), final
        unsigned short* bRim = buf0;
        unsigned short* bTt  = buf0 + matBytes / 2;
        unsigned short* bRtt = buf0 + 2 * (matBytes / 2);
        unsigned short* bIm  = buf0 + 3 * (matBytes / 2);
        prep4<<<4 * bpm + Bn / 4, 256, 0, stream>>>(
            im, tt, rim, rtt, bIm, bTt, bRim, bRtt, S_im, S_tt, diag, D, bpm);
        ggrid.z = 2;
        gemm_expsum<<<ggrid, 256, 0, stream>>>(bRim, bTt, S_im, bRtt, bIm, S_tt,
                                               lsc, offs, Bn, D);
    } else {
        // 2-buffer sequential fallback
        unsigned short* bA = buf0;
        unsigned short* bB = buf0 + matBytes / 2;
        // prep4 with only 2 matrices' worth of blocks would mis-map; use
        // convert2 + a tiny prep4 tail trick: zero/diag via prep4's tail only.
        prep4<<<Bn / 4, 256, 0, stream>>>(im, tt, rim, rtt,
                                          bA, bA, bA, bA, S_im, S_tt, diag, D, 0);
        convert2<<<2 * bpm, 256, 0, stream>>>(rim, bA, tt, bB, D, cpm);
        gemm_expsum<<<ggrid, 256, 0, stream>>>(bA, bB, S_im, bA, bB, S_im,
                                               lsc, offs, Bn, D);
        convert2<<<2 * bpm, 256, 0, stream>>>(rtt, bA, im, bB, D, cpm);
        gemm_expsum<<<ggrid, 256, 0, stream>>>(bA, bB, S_tt, bA, bB, S_tt,
                                               lsc, offs, Bn, D);
    }

    final_kernel<<<1, 256, 0, stream>>>(S_im, S_tt, diag, ru_im, ru_tt,
                                        l1_im, l1_tt, u_im, u_tt, lsc,
                                        (float*)d_out, Bn);
}

// Round 5
// 202.841 us; speedup vs baseline: 1.3038x; 1.1340x over previous
//
#include <hip/hip_runtime.h>
#include <hip/hip_bf16.h>

#define EPSF 1e-14f
#define RHOF 8.0f

typedef __attribute__((ext_vector_type(4))) float f32x4;
typedef __attribute__((ext_vector_type(2))) unsigned long long u64x2;

#define AS_GLOBAL __attribute__((address_space(1)))
#define AS_LDS    __attribute__((address_space(3)))

// fp8 packed layout. Tile = 128 rows x 32 cols fp8 = 4096 B = 256 units of
// 16 B. Unit u = r*2 + h holds row r's k-chunks {(2h)^m, (2h+1)^m}, m =
// (r>>2)&3 (8-B slot s of row r holds content chunk s^m). GEMM fragment read
// for (r, qd) is slot qd^m -> ds_read_b64 banks spread (<=2-way aliasing,
// free). global_load_lds deposits lane L's 16 B at base+L*16, so packed
// global order == LDS unit order.

// One dispatch: convert 4 matrices f32->fp8 packed, diag, zero S/red.
__global__ __launch_bounds__(256) void prep_fp8(
    const float* __restrict__ im,  const float* __restrict__ tt,
    const float* __restrict__ rim, const float* __restrict__ rtt,
    unsigned char* __restrict__ bIm,  unsigned char* __restrict__ bTt,
    unsigned char* __restrict__ bRim, unsigned char* __restrict__ bRtt,
    float* __restrict__ S_im, float* __restrict__ S_tt,
    float* __restrict__ diag, float* __restrict__ red,
    int D, int spm /* 8-row slabs per matrix */)
{
    __shared__ unsigned char L[8 * 1024];   // 8 rows x D fp8 (D<=1024)
    const int b = blockIdx.x;
    const int tid = threadIdx.x;
    const int nConv = 4 * spm;
    if (b < nConv) {
        int mIdx = b / spm;
        int slab = b - mIdx * spm;
        const float* src = (mIdx == 0) ? rim : (mIdx == 1) ? tt
                          : (mIdx == 2) ? rtt : im;
        unsigned char* dst = (mIdx == 0) ? bRim : (mIdx == 1) ? bTt
                            : (mIdx == 2) ? bRtt : bIm;
        const float* srow = src + (size_t)slab * 8 * D;
        // phase 1: fully-coalesced read, pack-convert to fp8, linear LDS image
        const int n4 = (8 * D) >> 2;                 // float4 count (2048)
        for (int idx = tid; idx < n4; idx += 256) {
            float4 v = *(const float4*)(srow + idx * 4);
            int pk = __builtin_amdgcn_cvt_pk_fp8_f32(v.x, v.y, 0, false);
            pk     = __builtin_amdgcn_cvt_pk_fp8_f32(v.z, v.w, pk, true);
            *(int*)&L[idx * 4] = pk;
        }
        __syncthreads();
        // phase 2: emit packed 16-B units; writes land in 256-B contiguous
        // segments (16 consecutive units per kb)
        const int kTiles = D >> 5;
        const int rb = (slab * 8) >> 7;
        const int r0loc = (slab * 8) & 127;
        for (int g = tid; g < (D >> 1); g += 256) {  // units per slab = D/2
            int kb = g >> 4;
            int rl = (g >> 1) & 7;
            int h  = g & 1;
            int r  = slab * 8 + rl;
            int m  = (r >> 2) & 3;
            int c0 = (2 * h) ^ m;
            const unsigned char* lb = &L[rl * D + kb * 32];
            u64x2 o;
            o.x = *(const unsigned long long*)(lb + c0 * 8);
            o.y = *(const unsigned long long*)(lb + (c0 ^ 1) * 8);
            char* outp = (char*)dst + (size_t)(rb * kTiles + kb) * 4096
                       + (size_t)((r0loc + rl) * 2 + h) * 16;
            *(u64x2*)outp = o;
        }
    } else {
        int db = b - nConv;                          // 0..Bn/4-1
        if (db == 0 && tid < 8) red[tid] = 0.f;      // loss partials + ticket
        if (tid < 4) { S_im[db * 4 + tid] = 0.f; S_tt[db * 4 + tid] = 0.f; }
        int row  = db * 4 + (tid >> 6);
        int lane = tid & 63;
        const float* a = rim + (size_t)row * D;
        const float* c = rtt + (size_t)row * D;
        float s = 0.f;
        for (int k = lane * 4; k < D; k += 256) {
            float4 av = *(const float4*)(a + k);
            float4 cv = *(const float4*)(c + k);
            s += av.x * cv.x + av.y * cv.y + av.z * cv.z + av.w * cv.w;
        }
        #pragma unroll
        for (int m2 = 1; m2 < 64; m2 <<= 1) s += __shfl_xor(s, m2, 64);
        if (lane == 0) diag[row] = s;
    }
}

// fp8 GEMM + exp + masked row-sum. z selects GEMM 0/1.
__global__ __launch_bounds__(256) void gemm_expsum(
    const unsigned char* __restrict__ A0, const unsigned char* __restrict__ B0,
    float* __restrict__ S0,
    const unsigned char* __restrict__ A1, const unsigned char* __restrict__ B1,
    float* __restrict__ S1,
    const float* __restrict__ logit_scale, const int* __restrict__ offset,
    int Bn, int D)
{
    const int z = blockIdx.z;
    const unsigned char* A = z ? A1 : A0;
    const unsigned char* B = z ? B1 : B0;
    float* S = z ? S1 : S0;

    __shared__ unsigned char As[4096];   // 128x32 fp8, unit-packed
    __shared__ unsigned char Bs[4096];

    const int tid  = threadIdx.x;
    const int wave = tid >> 6;
    const int lane = tid & 63;
    const int lo   = lane & 15;
    const int qd   = lane >> 4;
    const int m0   = (wave >> 1) * 64;
    const int n0   = (wave & 1) * 64;
    const int slot = qd ^ (lo >> 2);     // (ra>>2)&3 == (lo>>2)&3 for our rows

    const int kTiles = D >> 5;
    const unsigned char* Atile = A + (size_t)blockIdx.y * kTiles * 4096;
    const unsigned char* Btile = B + (size_t)blockIdx.x * kTiles * 4096;

    f32x4 acc[4][4];
    #pragma unroll
    for (int i = 0; i < 4; ++i)
        #pragma unroll
        for (int j = 0; j < 4; ++j)
            acc[i][j] = (f32x4){0.f, 0.f, 0.f, 0.f};

    for (int kb = 0; kb < kTiles; ++kb) {
        __builtin_amdgcn_global_load_lds(
            (const AS_GLOBAL unsigned int*)(Atile + tid * 16),
            (AS_LDS unsigned int*)&As[wave * 1024], 16, 0, 0);
        __builtin_amdgcn_global_load_lds(
            (const AS_GLOBAL unsigned int*)(Btile + tid * 16),
            (AS_LDS unsigned int*)&Bs[wave * 1024], 16, 0, 0);
        __syncthreads();

        long af[4], bq[4];
        #pragma unroll
        for (int t = 0; t < 4; ++t) {
            int ra = m0 + 16 * t + lo;
            af[t] = *(const long*)&As[ra * 32 + slot * 8];
            int rn = n0 + 16 * t + lo;
            bq[t] = *(const long*)&Bs[rn * 32 + slot * 8];
        }
        #pragma unroll
        for (int ti = 0; ti < 4; ++ti)
            #pragma unroll
            for (int tj = 0; tj < 4; ++tj)
                acc[ti][tj] = __builtin_amdgcn_mfma_f32_16x16x32_fp8_fp8(
                    af[ti], bq[tj], acc[ti][tj], 0, 0, 0);
        __syncthreads();

        Atile += 4096;
        Btile += 4096;
    }

    const float ls = logit_scale[0];
    const int offs = offset[0];
    const int rowBase = blockIdx.y * 128;
    const int colBase = blockIdx.x * 128;
    #pragma unroll
    for (int ti = 0; ti < 4; ++ti) {
        #pragma unroll
        for (int r = 0; r < 4; ++r) {
            int gi = rowBase + m0 + 16 * ti + 4 * qd + r;   // C/D row=quad*4+reg
            float rs = 0.f;
            #pragma unroll
            for (int tj = 0; tj < 4; ++tj) {
                int gj = colBase + n0 + 16 * tj + lo;        // C/D col=lane&15
                float e = __expf(ls * acc[ti][tj][r]);
                if (gj == gi + offs) e = 0.f;                // shifted diagonal
                rs += e;
            }
            #pragma unroll
            for (int m = 1; m < 16; m <<= 1) rs += __shfl_xor(rs, m, 64);
            if (lo == 0) atomicAdd(&S[gi], rs);
        }
    }
}

// 8-block reduction; last block (ticket) computes the scalar loss.
__global__ __launch_bounds__(256) void final_kernel(
    const float* __restrict__ S_im, const float* __restrict__ S_tt,
    const float* __restrict__ diag,
    const float* __restrict__ ru_im, const float* __restrict__ ru_tt,
    const float* __restrict__ l1_im, const float* __restrict__ l1_tt,
    const float* __restrict__ u_im,  const float* __restrict__ u_tt,
    const float* __restrict__ logit_scale, float* __restrict__ red,
    float* __restrict__ out, int Bn)
{
    const float ls = logit_scale[0];
    const float inv_rw = 1.0f / (float)(Bn - 1);
    const int gid = blockIdx.x * 256 + threadIdx.x;
    float pg = 0.f, lg = 0.f;
    for (int i = gid; i < Bn; i += 8 * 256) {
        float p1 = l1_im[i] / (u_im[i] + EPSF) + l1_tt[i] / (u_tt[i] + EPSF);
        float dd = expf(-ls * diag[i]);
        float p2 = dd * S_im[i] * inv_rw / (ru_im[i] + EPSF)
                 + dd * S_tt[i] * inv_rw / (ru_tt[i] + EPSF);
        pg += p1 + p2;
        lg += logf(u_im[i]) + logf(u_tt[i]);
    }
    __shared__ float sp[256], sl[256];
    sp[threadIdx.x] = pg; sl[threadIdx.x] = lg;
    __syncthreads();
    for (int s = 128; s > 0; s >>= 1) {
        if (threadIdx.x < s) { sp[threadIdx.x] += sp[threadIdx.x + s];
                               sl[threadIdx.x] += sl[threadIdx.x + s]; }
        __syncthreads();
    }
    if (threadIdx.x == 0) {
        atomicAdd(&red[0], sp[0]);
        atomicAdd(&red[1], sl[0]);
        __threadfence();
        int t = atomicAdd((int*)&red[2], 1);
        if (t == gridDim.x - 1) {
            float pgSum = atomicAdd(&red[0], 0.f);   // coherent read
            float lgSum = atomicAdd(&red[1], 0.f);
            float loss = ((pgSum / (float)Bn) * 0.5f) / ls
                       + RHOF / ls
                       + (lgSum / (float)Bn) * 0.5f / ls;
            out[0] = loss;
        }
    }
}

extern "C" void kernel_launch(void* const* d_in, const int* in_sizes, int n_in,
                              void* d_out, int out_size, void* d_ws, size_t ws_size,
                              hipStream_t stream) {
    const float* im    = (const float*)d_in[0];
    const float* tt    = (const float*)d_in[1];
    const float* rim   = (const float*)d_in[2];
    const float* rtt   = (const float*)d_in[3];
    const float* ru_im = (const float*)d_in[4];
    const float* ru_tt = (const float*)d_in[5];
    const float* l1_im = (const float*)d_in[6];
    const float* l1_tt = (const float*)d_in[7];
    const float* u_im  = (const float*)d_in[8];
    const float* u_tt  = (const float*)d_in[9];
    const float* lsc   = (const float*)d_in[10];
    const int*   offs  = (const int*)d_in[11];

    const int Bn = in_sizes[4];          // 4096
    const int D  = in_sizes[0] / Bn;     // 1024
    const int spm = Bn / 8;              // 8-row slabs per matrix

    char* base = (char*)d_ws;
    float* S_im = (float*)base;
    float* S_tt = S_im + Bn;
    float* diag = S_tt + Bn;
    float* red  = diag + Bn;             // [0]=pg, [1]=lg, [2]=ticket
    const size_t headBytes = (((size_t)(3 * Bn + 8) * sizeof(float)) + 255) & ~(size_t)255;
    const size_t matBytes  = (size_t)Bn * D;          // fp8: 1 B/elem
    unsigned char* buf0 = (unsigned char*)(base + headBytes);
    unsigned char* bRim = buf0;
    unsigned char* bTt  = buf0 + matBytes;
    unsigned char* bRtt = buf0 + 2 * matBytes;
    unsigned char* bIm  = buf0 + 3 * matBytes;

    prep_fp8<<<4 * spm + Bn / 4, 256, 0, stream>>>(
        im, tt, rim, rtt, bIm, bTt, bRim, bRtt, S_im, S_tt, diag, red, D, spm);

    dim3 ggrid(Bn / 128, Bn / 128, 2);
    gemm_expsum<<<ggrid, 256, 0, stream>>>(bRim, bTt, S_im, bRtt, bIm, S_tt,
                                           lsc, offs, Bn, D);

    final_kernel<<<8, 256, 0, stream>>>(S_im, S_tt, diag, ru_im, ru_tt,
                                        l1_im, l1_tt, u_im, u_tt, lsc,
                                        red, (float*)d_out, Bn);
}

// Round 6
// 199.982 us; speedup vs baseline: 1.3224x; 1.0143x over previous
//
#include <hip/hip_runtime.h>
#include <hip/hip_bf16.h>

#define EPSF 1e-14f
#define RHOF 8.0f

typedef __attribute__((ext_vector_type(4))) float f32x4;
typedef __attribute__((ext_vector_type(2))) unsigned long long u64x2;

#define AS_GLOBAL __attribute__((address_space(1)))
#define AS_LDS    __attribute__((address_space(3)))

// fp8 packed layout, BK=64. Tile = 128 rows x 64 cols fp8 = 8 KB = 512 units
// of 16 B. Row r holds 8 granules of 8 B; granule g stored at slot
// g ^ m(r), m(r) = (r>>1)&7. Unit u = r*4 + h holds slots {2h, 2h+1}.
// GEMM fragment read (16x16x32 fp8, sub-step s, quad qd) needs granule
// s*4+qd -> LDS byte r*64 + ((s^x2)*32 + xq*8), x2=(lo>>3)&1,
// xq=qd^((lo>>1)&3). Per 16-lane phase banks group
// (lo&1)*8 + ((s*4+qd)^(lo>>1)) is a bijection -> conflict-free.
// global_load_lds deposit order == packed global order (unit u at byte 16u).

__global__ __launch_bounds__(256) void prep_fp8(
    const float* __restrict__ im,  const float* __restrict__ tt,
    const float* __restrict__ rim, const float* __restrict__ rtt,
    unsigned char* __restrict__ bIm,  unsigned char* __restrict__ bTt,
    unsigned char* __restrict__ bRim, unsigned char* __restrict__ bRtt,
    float* __restrict__ S_im, float* __restrict__ S_tt,
    float* __restrict__ diag, float* __restrict__ red,
    int D, int spm /* 8-row slabs per matrix */)
{
    __shared__ unsigned char L[8 * 1024];   // 8 rows x D fp8 (D<=1024)
    const int b = blockIdx.x;
    const int tid = threadIdx.x;
    const int nConv = 4 * spm;
    if (b < nConv) {
        int mIdx = b / spm;
        int slab = b - mIdx * spm;
        const float* src = (mIdx == 0) ? rim : (mIdx == 1) ? tt
                          : (mIdx == 2) ? rtt : im;
        unsigned char* dst = (mIdx == 0) ? bRim : (mIdx == 1) ? bTt
                            : (mIdx == 2) ? bRtt : bIm;
        const float* srow = src + (size_t)slab * 8 * D;
        // phase 1: coalesced read, pack-convert to fp8, linear LDS image
        const int n4 = (8 * D) >> 2;
        for (int idx = tid; idx < n4; idx += 256) {
            float4 v = *(const float4*)(srow + idx * 4);
            int pk = __builtin_amdgcn_cvt_pk_fp8_f32(v.x, v.y, 0, false);
            pk     = __builtin_amdgcn_cvt_pk_fp8_f32(v.z, v.w, pk, true);
            *(int*)&L[idx * 4] = pk;
        }
        __syncthreads();
        // phase 2: emit packed 16-B units (BK=64 tiles)
        const int kTiles = D >> 6;
        const int rb = (slab * 8) >> 7;
        const int r0loc = (slab * 8) & 127;
        for (int g = tid; g < (D >> 1); g += 256) {  // units per slab = D/2
            int kb  = g >> 5;                        // 32 units per (slab,kb)
            int rem = g & 31;
            int rl  = rem >> 2;
            int h   = rem & 3;
            int r   = slab * 8 + rl;
            int m   = (r >> 1) & 7;
            int g0  = (2 * h) ^ m;                   // slot 2h content granule
            const unsigned char* lb = &L[rl * D + kb * 64];
            u64x2 o;
            o.x = *(const unsigned long long*)(lb + g0 * 8);
            o.y = *(const unsigned long long*)(lb + (g0 ^ 1) * 8);
            char* outp = (char*)dst
                       + ((size_t)(rb * kTiles + kb) * 512
                          + (size_t)(r0loc + rl) * 4 + h) * 16;
            *(u64x2*)outp = o;
        }
    } else {
        int db = b - nConv;
        if (db == 0 && tid < 8) red[tid] = 0.f;
        if (tid < 4) { S_im[db * 4 + tid] = 0.f; S_tt[db * 4 + tid] = 0.f; }
        int row  = db * 4 + (tid >> 6);
        int lane = tid & 63;
        const float* a = rim + (size_t)row * D;
        const float* c = rtt + (size_t)row * D;
        float s = 0.f;
        for (int k = lane * 4; k < D; k += 256) {
            float4 av = *(const float4*)(a + k);
            float4 cv = *(const float4*)(c + k);
            s += av.x * cv.x + av.y * cv.y + av.z * cv.z + av.w * cv.w;
        }
        #pragma unroll
        for (int m2 = 1; m2 < 64; m2 <<= 1) s += __shfl_xor(s, m2, 64);
        if (lane == 0) diag[row] = s;
    }
}

// fp8 GEMM (BK=64) + exp + masked row-sum. z selects GEMM 0/1.
__global__ __launch_bounds__(256) void gemm_expsum(
    const unsigned char* __restrict__ A0, const unsigned char* __restrict__ B0,
    float* __restrict__ S0,
    const unsigned char* __restrict__ A1, const unsigned char* __restrict__ B1,
    float* __restrict__ S1,
    const float* __restrict__ logit_scale, const int* __restrict__ offset,
    int Bn, int D)
{
    const int z = blockIdx.z;
    const unsigned char* A = z ? A1 : A0;
    const unsigned char* B = z ? B1 : B0;
    float* S = z ? S1 : S0;

    __shared__ unsigned char As[8192];   // 128x64 fp8, unit-packed
    __shared__ unsigned char Bs[8192];

    const int tid  = threadIdx.x;
    const int wave = tid >> 6;
    const int lane = tid & 63;
    const int lo   = lane & 15;
    const int qd   = lane >> 4;
    const int m0   = (wave >> 1) * 64;
    const int n0   = (wave & 1) * 64;
    const int x2   = (lo >> 3) & 1;            // bit2 of slot xor
    const int xq   = qd ^ ((lo >> 1) & 3);     // low bits of slot
    const int off0 = x2 * 32 + xq * 8;         // sub-step 0 byte offset
    const int off1 = (1 - x2) * 32 + xq * 8;   // sub-step 1 byte offset

    const int kTiles = D >> 6;
    const unsigned char* Atile = A + (size_t)blockIdx.y * kTiles * 8192;
    const unsigned char* Btile = B + (size_t)blockIdx.x * kTiles * 8192;

    f32x4 acc[4][4];
    #pragma unroll
    for (int i = 0; i < 4; ++i)
        #pragma unroll
        for (int j = 0; j < 4; ++j)
            acc[i][j] = (f32x4){0.f, 0.f, 0.f, 0.f};

    for (int kb = 0; kb < kTiles; ++kb) {
        #pragma unroll
        for (int j = 0; j < 4; ++j) {
            int goff = (j * 256 + tid) * 16;          // global byte offset
            int loff = j * 4096 + wave * 1024;        // wave-uniform LDS base
            __builtin_amdgcn_global_load_lds(
                (const AS_GLOBAL unsigned int*)(Atile + goff),
                (AS_LDS unsigned int*)&As[loff], 16, 0, 0);
            __builtin_amdgcn_global_load_lds(
                (const AS_GLOBAL unsigned int*)(Btile + goff),
                (AS_LDS unsigned int*)&Bs[loff], 16, 0, 0);
        }
        __syncthreads();

        long af0[4], af1[4], bq0[4], bq1[4];
        #pragma unroll
        for (int t = 0; t < 4; ++t) {
            int ra = (m0 + 16 * t + lo) * 64;
            af0[t] = *(const long*)&As[ra + off0];
            af1[t] = *(const long*)&As[ra + off1];
            int rn = (n0 + 16 * t + lo) * 64;
            bq0[t] = *(const long*)&Bs[rn + off0];
            bq1[t] = *(const long*)&Bs[rn + off1];
        }
        #pragma unroll
        for (int ti = 0; ti < 4; ++ti)
            #pragma unroll
            for (int tj = 0; tj < 4; ++tj) {
                acc[ti][tj] = __builtin_amdgcn_mfma_f32_16x16x32_fp8_fp8(
                    af0[ti], bq0[tj], acc[ti][tj], 0, 0, 0);
                acc[ti][tj] = __builtin_amdgcn_mfma_f32_16x16x32_fp8_fp8(
                    af1[ti], bq1[tj], acc[ti][tj], 0, 0, 0);
            }
        __syncthreads();

        Atile += 8192;
        Btile += 8192;
    }

    const float ls = logit_scale[0];
    const int offs = offset[0];
    const int rowBase = blockIdx.y * 128;
    const int colBase = blockIdx.x * 128;
    #pragma unroll
    for (int ti = 0; ti < 4; ++ti) {
        #pragma unroll
        for (int r = 0; r < 4; ++r) {
            int gi = rowBase + m0 + 16 * ti + 4 * qd + r;   // C/D row=quad*4+reg
            float rs = 0.f;
            #pragma unroll
            for (int tj = 0; tj < 4; ++tj) {
                int gj = colBase + n0 + 16 * tj + lo;        // C/D col=lane&15
                float e = __expf(ls * acc[ti][tj][r]);
                if (gj == gi + offs) e = 0.f;                // shifted diagonal
                rs += e;
            }
            #pragma unroll
            for (int m = 1; m < 16; m <<= 1) rs += __shfl_xor(rs, m, 64);
            if (lo == 0) atomicAdd(&S[gi], rs);
        }
    }
}

// 8-block reduction; last block (ticket) computes the scalar loss.
__global__ __launch_bounds__(256) void final_kernel(
    const float* __restrict__ S_im, const float* __restrict__ S_tt,
    const float* __restrict__ diag,
    const float* __restrict__ ru_im, const float* __restrict__ ru_tt,
    const float* __restrict__ l1_im, const float* __restrict__ l1_tt,
    const float* __restrict__ u_im,  const float* __restrict__ u_tt,
    const float* __restrict__ logit_scale, float* __restrict__ red,
    float* __restrict__ out, int Bn)
{
    const float ls = logit_scale[0];
    const float inv_rw = 1.0f / (float)(Bn - 1);
    const int gid = blockIdx.x * 256 + threadIdx.x;
    float pg = 0.f, lg = 0.f;
    for (int i = gid; i < Bn; i += 8 * 256) {
        float p1 = l1_im[i] / (u_im[i] + EPSF) + l1_tt[i] / (u_tt[i] + EPSF);
        float dd = expf(-ls * diag[i]);
        float p2 = dd * S_im[i] * inv_rw / (ru_im[i] + EPSF)
                 + dd * S_tt[i] * inv_rw / (ru_tt[i] + EPSF);
        pg += p1 + p2;
        lg += logf(u_im[i]) + logf(u_tt[i]);
    }
    __shared__ float sp[256], sl[256];
    sp[threadIdx.x] = pg; sl[threadIdx.x] = lg;
    __syncthreads();
    for (int s = 128; s > 0; s >>= 1) {
        if (threadIdx.x < s) { sp[threadIdx.x] += sp[threadIdx.x + s];
                               sl[threadIdx.x] += sl[threadIdx.x + s]; }
        __syncthreads();
    }
    if (threadIdx.x == 0) {
        atomicAdd(&red[0], sp[0]);
        atomicAdd(&red[1], sl[0]);
        __threadfence();
        int t = atomicAdd((int*)&red[2], 1);
        if (t == gridDim.x - 1) {
            float pgSum = atomicAdd(&red[0], 0.f);
            float lgSum = atomicAdd(&red[1], 0.f);
            float loss = ((pgSum / (float)Bn) * 0.5f) / ls
                       + RHOF / ls
                       + (lgSum / (float)Bn) * 0.5f / ls;
            out[0] = loss;
        }
    }
}

extern "C" void kernel_launch(void* const* d_in, const int* in_sizes, int n_in,
                              void* d_out, int out_size, void* d_ws, size_t ws_size,
                              hipStream_t stream) {
    const float* im    = (const float*)d_in[0];
    const float* tt    = (const float*)d_in[1];
    const float* rim   = (const float*)d_in[2];
    const float* rtt   = (const float*)d_in[3];
    const float* ru_im = (const float*)d_in[4];
    const float* ru_tt = (const float*)d_in[5];
    const float* l1_im = (const float*)d_in[6];
    const float* l1_tt = (const float*)d_in[7];
    const float* u_im  = (const float*)d_in[8];
    const float* u_tt  = (const float*)d_in[9];
    const float* lsc   = (const float*)d_in[10];
    const int*   offs  = (const int*)d_in[11];

    const int Bn = in_sizes[4];          // 4096
    const int D  = in_sizes[0] / Bn;     // 1024
    const int spm = Bn / 8;              // 8-row slabs per matrix

    char* base = (char*)d_ws;
    float* S_im = (float*)base;
    float* S_tt = S_im + Bn;
    float* diag = S_tt + Bn;
    float* red  = diag + Bn;             // [0]=pg, [1]=lg, [2]=ticket
    const size_t headBytes = (((size_t)(3 * Bn + 8) * sizeof(float)) + 255) & ~(size_t)255;
    const size_t matBytes  = (size_t)Bn * D;          // fp8: 1 B/elem
    unsigned char* buf0 = (unsigned char*)(base + headBytes);
    unsigned char* bRim = buf0;
    unsigned char* bTt  = buf0 + matBytes;
    unsigned char* bRtt = buf0 + 2 * matBytes;
    unsigned char* bIm  = buf0 + 3 * matBytes;

    prep_fp8<<<4 * spm + Bn / 4, 256, 0, stream>>>(
        im, tt, rim, rtt, bIm, bTt, bRim, bRtt, S_im, S_tt, diag, red, D, spm);

    dim3 ggrid(Bn / 128, Bn / 128, 2);
    gemm_expsum<<<ggrid, 256, 0, stream>>>(bRim, bTt, S_im, bRtt, bIm, S_tt,
                                           lsc, offs, Bn, D);

    final_kernel<<<8, 256, 0, stream>>>(S_im, S_tt, diag, ru_im, ru_tt,
                                        l1_im, l1_tt, u_im, u_tt, lsc,
                                        red, (float*)d_out, Bn);
}